// Round 11
// baseline (971.749 us; speedup 1.0000x reference)
//
#include <hip/hip_runtime.h>
#include <math.h>

#define NN 100000
#define NE 1600000
#define NG 1000
#define IN_DIM 64
#define HID 128
#define EXD 32
#define OUTD 10
#define BN_EPS 1e-5f

#define SCAN_B 256
#define NBLK ((NN + SCAN_B - 1) / SCAN_B)   // 391

// XCD-partitioned edge placement (scattered csr writes stay XCD-local)
#define FCH 128
#define FCE (NE / FCH)          // 12500 edges per chunk
#define PR  ((NN + 7) / 8)      // 12500 nodes per part

#define AGB 12500               // gather blocks (8 nodes each, exact)

typedef __attribute__((ext_vector_type(8))) short bf16x8;
typedef __attribute__((ext_vector_type(4))) float f32x4;

__device__ __forceinline__ float bf2f(unsigned short h) {
    return __uint_as_float((unsigned int)h << 16);
}
__device__ __forceinline__ unsigned short f2bf(float f) {
    unsigned int u = __float_as_uint(f);
    u += 0x7fffu + ((u >> 16) & 1u);        // round to nearest even
    return (unsigned short)(u >> 16);
}

// ---------------- degree + per-edge position (one atomic pass) ----------------
// UNPARTITIONED (R10 post-mortem: atomic writeback is placement-invariant;
// partitioning only added dst re-reads + epos write amplification).

__global__ void degpos_kernel(const int* __restrict__ dst, int* __restrict__ deg,
                              unsigned char* __restrict__ epos) {
    int e = blockIdx.x * 256 + threadIdx.x;
    if (e < NE) epos[e] = (unsigned char)atomicAdd(&deg[dst[e]], 1);
}

// exclusive scan of deg -> row_start; also dinv = rsqrt(deg+1)
__global__ void scan1_kernel(const int* __restrict__ deg, int* __restrict__ row_start,
                             int* __restrict__ bsums, float* __restrict__ dinv) {
    __shared__ int s[SCAN_B];
    int t = threadIdx.x;
    int i = blockIdx.x * SCAN_B + t;
    int v = (i < NN) ? deg[i] : 0;
    if (i < NN) dinv[i] = rsqrtf((float)v + 1.0f);   // +1 self loop
    s[t] = v;
    __syncthreads();
    for (int off = 1; off < SCAN_B; off <<= 1) {
        int u = (t >= off) ? s[t - off] : 0;
        __syncthreads();
        s[t] += u;
        __syncthreads();
    }
    if (i < NN) row_start[i] = s[t] - v;
    if (t == SCAN_B - 1) bsums[blockIdx.x] = s[t];
}

__global__ void scan2_kernel(int* __restrict__ bsums) {
    __shared__ int s[512];
    int t = threadIdx.x;
    int v = (t < NBLK) ? bsums[t] : 0;
    s[t] = v;
    __syncthreads();
    for (int off = 1; off < 512; off <<= 1) {
        int u = (t >= off) ? s[t - off] : 0;
        __syncthreads();
        s[t] += u;
        __syncthreads();
    }
    if (t < NBLK) bsums[t] = s[t] - v;
}

__global__ void scan3_kernel(int* __restrict__ row_start, const int* __restrict__ bsums) {
    int i = blockIdx.x * 256 + threadIdx.x;
    if (i < NN) row_start[i] += bsums[i >> 8];
    if (i == 0) row_start[NN] = NE;
}

// ---------------- fused prep: fill + gstart + cvt + wprep (one launch) ----------------

struct WPack {
    const float* w[10];
    int K[10];
};

#define FILL_B (FCH * 8)                       // 1024
#define GST_B  NBLK                            // 391
#define CVT_B  ((NN * 16 + 255) / 256)         // 6250
#define WPREP_B 640                            // 10 matrices x 64

__global__ void prep_kernel(const int* __restrict__ src, const int* __restrict__ dst,
                            const int* __restrict__ row_start,
                            const unsigned char* __restrict__ epos,
                            int* __restrict__ csr_src,
                            const int* __restrict__ batch, int* __restrict__ gstart,
                            const float* __restrict__ x, unsigned short* __restrict__ xb,
                            WPack wp, unsigned short* __restrict__ wf) {
    int b = blockIdx.x;
    int tid = threadIdx.x;
    if (b < FILL_B) {
        // edge placement: slot = row_start[dst] + epos[e]; partitioned writes
        int part = b & 7;
        int lo = part * PR, hi = min(lo + PR, NN);
        int e0 = (b >> 3) * FCE;
        for (int e = e0 + tid; e < e0 + FCE; e += 256) {
            int d = dst[e];
            if (d >= lo && d < hi) csr_src[row_start[d] + (int)epos[e]] = src[e];
        }
    } else if (b < FILL_B + GST_B) {
        int n = (b - FILL_B) * 256 + tid;
        if (n >= NN) return;
        int bc = batch[n];
        int bp = (n == 0) ? -1 : batch[n - 1];
        for (int g = bp + 1; g <= bc; ++g) gstart[g] = n;
        if (n == NN - 1)
            for (int g = bc + 1; g <= NG; ++g) gstart[g] = NN;
    } else if (b < FILL_B + GST_B + CVT_B) {
        int i = (b - FILL_B - GST_B) * 256 + tid;
        if (i >= NN * 16) return;
        float4 v = ((const float4*)x)[i];
        ushort4 o;
        o.x = f2bf(v.x); o.y = f2bf(v.y); o.z = f2bf(v.z); o.w = f2bf(v.w);
        ((ushort4*)xb)[i] = o;
    } else {
        int b2 = b - FILL_B - GST_B - CVT_B;
        int m = b2 >> 6;
        int idx = ((b2 & 63) << 8) + tid;
        int K = wp.K[m];
        if (idx >= K * 128) return;
        int k = idx >> 7, n = idx & 127;
        wf[m * 16384 + (((k >> 3) * 128 + n) << 3) + (k & 7)] = f2bf(wp.w[m][idx]);
    }
}

// ---------------- GCN aggregation: pull-gather + fused BN partial stats ----------------
// 8 nodes per block, 32 lanes per node, lane covers feats [4*lane .. 4*lane+3].
// Epilogue: block-level LDS reduction -> per-block partial sum/sumsq (coalesced).
__launch_bounds__(256)
__global__ void gather_kernel(const int* __restrict__ row_start,
                              const int* __restrict__ csr_src,
                              const unsigned short* __restrict__ xwb,
                              const float* __restrict__ dinv,
                              const float* __restrict__ b,
                              unsigned short* __restrict__ aggb,
                              float* __restrict__ psum, float* __restrict__ psq) {
    __shared__ float rsm[8][128];
    __shared__ float rqm[8][128];
    int node = blockIdx.x * 8 + (threadIdx.x >> 5);
    int lane = threadIdx.x & 31;
    int rs = row_start[node], re = row_start[node + 1];
    float d = dinv[node];
    int fo = lane << 2;
    ushort4 sv = *(const ushort4*)(xwb + (size_t)node * HID + fo);
    float4 accE = make_float4(0.f, 0.f, 0.f, 0.f);
    int e = rs;
    for (; e + 7 < re; e += 8) {
        int sI[8];
#pragma unroll
        for (int j = 0; j < 8; ++j) sI[j] = csr_src[e + j];
        float cI[8];
        ushort4 rI[8];
#pragma unroll
        for (int j = 0; j < 8; ++j) {
            cI[j] = dinv[sI[j]];
            rI[j] = *(const ushort4*)(xwb + (size_t)sI[j] * HID + fo);
        }
#pragma unroll
        for (int j = 0; j < 8; ++j) {
            accE.x += cI[j] * bf2f(rI[j].x);
            accE.y += cI[j] * bf2f(rI[j].y);
            accE.z += cI[j] * bf2f(rI[j].z);
            accE.w += cI[j] * bf2f(rI[j].w);
        }
    }
    for (; e + 1 < re; e += 2) {
        int s0 = csr_src[e], s1 = csr_src[e + 1];
        float c0 = dinv[s0], c1 = dinv[s1];
        ushort4 r0 = *(const ushort4*)(xwb + (size_t)s0 * HID + fo);
        ushort4 r1 = *(const ushort4*)(xwb + (size_t)s1 * HID + fo);
        accE.x += c0 * bf2f(r0.x) + c1 * bf2f(r1.x);
        accE.y += c0 * bf2f(r0.y) + c1 * bf2f(r1.y);
        accE.z += c0 * bf2f(r0.z) + c1 * bf2f(r1.z);
        accE.w += c0 * bf2f(r0.w) + c1 * bf2f(r1.w);
    }
    if (e < re) {
        int s0 = csr_src[e];
        float c0 = dinv[s0];
        ushort4 r0 = *(const ushort4*)(xwb + (size_t)s0 * HID + fo);
        accE.x += c0 * bf2f(r0.x);
        accE.y += c0 * bf2f(r0.y);
        accE.z += c0 * bf2f(r0.z);
        accE.w += c0 * bf2f(r0.w);
    }
    float d2 = d * d;
    ushort4 o;
    o.x = f2bf(d * accE.x + d2 * bf2f(sv.x) + b[fo + 0]);
    o.y = f2bf(d * accE.y + d2 * bf2f(sv.y) + b[fo + 1]);
    o.z = f2bf(d * accE.z + d2 * bf2f(sv.z) + b[fo + 2]);
    o.w = f2bf(d * accE.w + d2 * bf2f(sv.w) + b[fo + 3]);
    *(ushort4*)(aggb + (size_t)node * HID + fo) = o;

    // ---- fused BN partial stats (on the bf16-rounded values, matching old bn_stats) ----
    float v0 = bf2f(o.x), v1 = bf2f(o.y), v2 = bf2f(o.z), v3 = bf2f(o.w);
    int sub = threadIdx.x >> 5;
    rsm[sub][fo + 0] = v0; rsm[sub][fo + 1] = v1;
    rsm[sub][fo + 2] = v2; rsm[sub][fo + 3] = v3;
    rqm[sub][fo + 0] = v0 * v0; rqm[sub][fo + 1] = v1 * v1;
    rqm[sub][fo + 2] = v2 * v2; rqm[sub][fo + 3] = v3 * v3;
    __syncthreads();
    int t = threadIdx.x;
    if (t < 128) {
        float s = 0.f, q = 0.f;
#pragma unroll
        for (int i = 0; i < 8; ++i) { s += rsm[i][t]; q += rqm[i][t]; }
        psum[(size_t)blockIdx.x * 128 + t] = s;
        psq[(size_t)blockIdx.x * 128 + t] = q;
    }
}

// reduce per-block partials -> gsum/gsq (atomicAdd over 32 blocks only)
__global__ void stats_reduce_kernel(const float* __restrict__ psum,
                                    const float* __restrict__ psq,
                                    float* __restrict__ gsum, float* __restrict__ gsq) {
    int t = threadIdx.x;            // 256
    int c = t & 127;
    bool isq = t >= 128;
    const float* p = isq ? psq : psum;
    float s = 0.f;
    for (int bi = blockIdx.x; bi < AGB; bi += 32)
        s += p[(size_t)bi * 128 + c];
    atomicAdd(isq ? &gsq[c] : &gsum[c], s);
}

// ---------------- MFMA GEMM (bf16 in, f32 acc, bf16 out) ----------------
// Block: 256 thr / 4 waves; tile 128 rows x 128 cols; wave owns 32 rows in K-loop.
// W (pre-formatted wf) staged into LDS per pass; B-frags via ds_read_b128.
// LDS buffer reused for epilogue C tile (barrier-separated) -> 4 blocks/CU.
// mode 2: target = bf16(A1 @ Wa)
// mode 1: BN finalize in-kernel (scl/shf from gsum/gsq/g/be into LDS);
//         ox = relu(A1*scl+shf); t = ox@Wa + A2@Wb + b1 + b2; z = sigmoid(t);
//         target = bf16(z*ox + (1-z)*target)    (target aliases A2)
#define CS_STRIDE 136
#define LW_STRIDE 1032          // shorts per k-chunk (1024 data + 8 pad)
__launch_bounds__(256, 4)
__global__ void mgemm_kernel(const unsigned short* __restrict__ A1,
                             const unsigned short* __restrict__ wfA, int K1,
                             const unsigned short* A2,
                             const unsigned short* __restrict__ wfB, int K2,
                             const float* __restrict__ bias1, const float* __restrict__ bias2,
                             const unsigned short* outx,
                             const float* __restrict__ gsum, const float* __restrict__ gsq,
                             const float* __restrict__ gw, const float* __restrict__ bew,
                             unsigned short* target, int mode) {
    __shared__ unsigned short sm[128 * CS_STRIDE];   // W-stage / C-stage
    __shared__ float sclS[128], shfS[128];
    int tid = threadIdx.x;
    int lane = tid & 63;
    int wv = tid >> 6;
    int lane15 = lane & 15;
    int q = lane >> 4;
    int m0 = blockIdx.x * 128 + wv * 32;

    if (mode == 1 && tid < 128) {
        float mu = gsum[tid] * (1.0f / NN);
        float var = gsq[tid] * (1.0f / NN) - mu * mu;
        float sc = gw[tid] * rsqrtf(var + BN_EPS);
        sclS[tid] = sc;
        shfS[tid] = bew[tid] - mu * sc;
    }

    f32x4 acc[2][8];
#pragma unroll
    for (int r = 0; r < 2; ++r)
#pragma unroll
        for (int nt = 0; nt < 8; ++nt)
            acc[r][nt] = (f32x4){0.f, 0.f, 0.f, 0.f};

    bf16x8 zf = {0, 0, 0, 0, 0, 0, 0, 0};

    for (int p = 0; p < 2; ++p) {
        const unsigned short* A = p ? A2 : A1;
        const unsigned short* wf = p ? wfB : wfA;
        int K = p ? K2 : K1;
        if (K == 0) continue;
        bool bnA = (mode == 1) && (p == 0);
        __syncthreads();
        for (int g = tid; g < K * 16; g += 256) {
            int c = g >> 7, off = (g & 127) << 3;
            *(bf16x8*)&sm[c * LW_STRIDE + off] = *(const bf16x8*)&wf[(c << 10) + off];
        }
        __syncthreads();
        int row0 = m0 + lane15;
        const unsigned short* a0p = A + (size_t)row0 * K + (q << 3);
        const unsigned short* a1p = a0p + (size_t)16 * K;
        bool g0 = row0 < NN, g1 = (row0 + 16) < NN;
#pragma unroll 4
        for (int k0 = 0; k0 < K; k0 += 32) {
            bf16x8 af0 = zf, af1 = zf;
            if (g0) af0 = *(const bf16x8*)(a0p + k0);
            if (g1) af1 = *(const bf16x8*)(a1p + k0);
            if (bnA) {
                int kb = k0 + (q << 3);
                float4 s4a = *(const float4*)&sclS[kb];
                float4 s4b = *(const float4*)&sclS[kb + 4];
                float4 h4a = *(const float4*)&shfS[kb];
                float4 h4b = *(const float4*)&shfS[kb + 4];
                float sv[8] = {s4a.x, s4a.y, s4a.z, s4a.w, s4b.x, s4b.y, s4b.z, s4b.w};
                float hv[8] = {h4a.x, h4a.y, h4a.z, h4a.w, h4b.x, h4b.y, h4b.z, h4b.w};
#pragma unroll
                for (int j = 0; j < 8; ++j) {
                    af0[j] = (short)f2bf(fmaxf(bf2f((unsigned short)af0[j]) * sv[j] + hv[j], 0.f));
                    af1[j] = (short)f2bf(fmaxf(bf2f((unsigned short)af1[j]) * sv[j] + hv[j], 0.f));
                }
            }
            const unsigned short* wb = &sm[((k0 >> 3) + q) * LW_STRIDE + (lane15 << 3)];
#pragma unroll
            for (int nt = 0; nt < 8; ++nt) {
                bf16x8 bf = *(const bf16x8*)(wb + nt * 128);
                acc[0][nt] = __builtin_amdgcn_mfma_f32_16x16x32_bf16(af0, bf, acc[0][nt], 0, 0, 0);
                acc[1][nt] = __builtin_amdgcn_mfma_f32_16x16x32_bf16(af1, bf, acc[1][nt], 0, 0, 0);
            }
        }
    }
    __syncthreads();

    if (mode == 1) {
        float bsum[8];
#pragma unroll
        for (int nt = 0; nt < 8; ++nt)
            bsum[nt] = bias1[nt * 16 + lane15] + bias2[nt * 16 + lane15];
#pragma unroll
        for (int r = 0; r < 2; ++r)
#pragma unroll
            for (int nt = 0; nt < 8; ++nt)
#pragma unroll
                for (int g = 0; g < 4; ++g) {
                    int rr = wv * 32 + r * 16 + q * 4 + g;
                    sm[rr * CS_STRIDE + nt * 16 + lane15] = f2bf(acc[r][nt][g] + bsum[nt]);
                }
    } else {
#pragma unroll
        for (int r = 0; r < 2; ++r)
#pragma unroll
            for (int nt = 0; nt < 8; ++nt)
#pragma unroll
                for (int g = 0; g < 4; ++g) {
                    int rr = wv * 32 + r * 16 + q * 4 + g;
                    sm[rr * CS_STRIDE + nt * 16 + lane15] = f2bf(acc[r][nt][g]);
                }
    }
    __syncthreads();

#pragma unroll
    for (int i = 0; i < 8; ++i) {
        int rt = (tid >> 4) + i * 16;
        int ch = tid & 15;
        int row = blockIdx.x * 128 + rt;
        if (row >= NN) continue;
        bf16x8 c = *(const bf16x8*)(sm + rt * CS_STRIDE + (ch << 3));
        size_t off = (size_t)row * HID + (ch << 3);
        if (mode == 1) {
            int cb = ch << 3;
            float4 s4a = *(const float4*)&sclS[cb];
            float4 s4b = *(const float4*)&sclS[cb + 4];
            float4 h4a = *(const float4*)&shfS[cb];
            float4 h4b = *(const float4*)&shfS[cb + 4];
            float sv[8] = {s4a.x, s4a.y, s4a.z, s4a.w, s4b.x, s4b.y, s4b.z, s4b.w};
            float hv[8] = {h4a.x, h4a.y, h4a.z, h4a.w, h4b.x, h4b.y, h4b.z, h4b.w};
            bf16x8 oxv = *(const bf16x8*)(outx + off);
            bf16x8 ixv = *(const bf16x8*)(target + off);
            bf16x8 o;
#pragma unroll
            for (int j = 0; j < 8; ++j) {
                float t = bf2f((unsigned short)c[j]);
                float z = 1.0f / (1.0f + expf(-t));
                float ox = fmaxf(bf2f((unsigned short)oxv[j]) * sv[j] + hv[j], 0.f);
                float h = z * ox + (1.0f - z) * bf2f((unsigned short)ixv[j]);
                o[j] = (short)f2bf(h);
            }
            *(bf16x8*)(target + off) = o;
        } else {
            *(bf16x8*)(target + off) = c;
        }
    }
}

// ---------------- dual-output GEMM for layer 1 (K=64, two W sets) ----------------
__launch_bounds__(256, 2)
__global__ void mgemm2_kernel(const unsigned short* __restrict__ A,
                              const unsigned short* __restrict__ wfA,
                              const unsigned short* __restrict__ wfB,
                              unsigned short* __restrict__ t0,
                              unsigned short* __restrict__ t1) {
    __shared__ unsigned short sm[128 * CS_STRIDE];
    int tid = threadIdx.x;
    int lane = tid & 63;
    int wv = tid >> 6;
    int lane15 = lane & 15;
    int q = lane >> 4;
    int m0 = blockIdx.x * 128 + wv * 32;

    for (int g = tid; g < 2048; g += 256) {
        int w = g >> 10;
        int c = (g >> 7) & 7;
        int off = (g & 127) << 3;
        const unsigned short* wf = w ? wfB : wfA;
        *(bf16x8*)&sm[(w * 8 + c) * LW_STRIDE + off] = *(const bf16x8*)&wf[(c << 10) + off];
    }
    __syncthreads();

    f32x4 acc[2][2][8];
#pragma unroll
    for (int w = 0; w < 2; ++w)
#pragma unroll
        for (int r = 0; r < 2; ++r)
#pragma unroll
            for (int nt = 0; nt < 8; ++nt)
                acc[w][r][nt] = (f32x4){0.f, 0.f, 0.f, 0.f};

    bf16x8 zf = {0, 0, 0, 0, 0, 0, 0, 0};
    int row0 = m0 + lane15;
    const unsigned short* a0p = A + (size_t)row0 * IN_DIM + (q << 3);
    const unsigned short* a1p = a0p + (size_t)16 * IN_DIM;
    bool g0 = row0 < NN, g1 = (row0 + 16) < NN;
#pragma unroll
    for (int k0 = 0; k0 < IN_DIM; k0 += 32) {
        bf16x8 af0 = zf, af1 = zf;
        if (g0) af0 = *(const bf16x8*)(a0p + k0);
        if (g1) af1 = *(const bf16x8*)(a1p + k0);
#pragma unroll
        for (int w = 0; w < 2; ++w) {
            const unsigned short* wb = &sm[(w * 8 + (k0 >> 3) + q) * LW_STRIDE + (lane15 << 3)];
#pragma unroll
            for (int nt = 0; nt < 8; ++nt) {
                bf16x8 bf = *(const bf16x8*)(wb + nt * 128);
                acc[w][0][nt] = __builtin_amdgcn_mfma_f32_16x16x32_bf16(af0, bf, acc[w][0][nt], 0, 0, 0);
                acc[w][1][nt] = __builtin_amdgcn_mfma_f32_16x16x32_bf16(af1, bf, acc[w][1][nt], 0, 0, 0);
            }
        }
    }

    for (int w = 0; w < 2; ++w) {
        unsigned short* target = w ? t1 : t0;
        __syncthreads();
#pragma unroll
        for (int r = 0; r < 2; ++r)
#pragma unroll
            for (int nt = 0; nt < 8; ++nt)
#pragma unroll
                for (int g = 0; g < 4; ++g) {
                    int rr = wv * 32 + r * 16 + q * 4 + g;
                    sm[rr * CS_STRIDE + nt * 16 + lane15] = f2bf(acc[w][r][nt][g]);
                }
        __syncthreads();
#pragma unroll
        for (int i = 0; i < 8; ++i) {
            int rt = (tid >> 4) + i * 16;
            int ch = tid & 15;
            int row = blockIdx.x * 128 + rt;
            if (row >= NN) continue;
            bf16x8 c = *(const bf16x8*)(sm + rt * CS_STRIDE + (ch << 3));
            *(bf16x8*)(target + (size_t)row * HID + (ch << 3)) = c;
        }
    }
}

// ---------------- pooling (segment-based, bf16 input) ----------------

__global__ void pool_kernel(const unsigned short* __restrict__ h,
                            const int* __restrict__ gstart,
                            float* __restrict__ pool) {
    __shared__ float red[8][128];
    int g = blockIdx.x, t = threadIdx.x;
    int lane = t & 31, sub = t >> 5;
    int s = gstart[g], e = gstart[g + 1];
    float4 acc = make_float4(0.f, 0.f, 0.f, 0.f);
    for (int r = s + sub; r < e; r += 8) {
        ushort4 v = *(const ushort4*)(h + (size_t)r * HID + (lane << 2));
        acc.x += bf2f(v.x); acc.y += bf2f(v.y);
        acc.z += bf2f(v.z); acc.w += bf2f(v.w);
    }
    *(float4*)&red[sub][lane << 2] = acc;
    __syncthreads();
    if (t < 128) {
        float a = 0.f;
#pragma unroll
        for (int i = 0; i < 8; ++i) a += red[i][t];
        pool[(size_t)g * HID + t] = a / (float)max(e - s, 1);
    }
}

// ---------------- MLP head ----------------

__global__ void head_kernel(const float* __restrict__ pool1, const float* __restrict__ pool2,
                            const float* __restrict__ pool3,
                            const float* __restrict__ eF,
                            const float* __restrict__ fc1W, const float* __restrict__ fc1b,
                            const float* __restrict__ fc3W, const float* __restrict__ fc3b,
                            float* __restrict__ out) {
    __shared__ float hg[3 * HID + EXD];
    __shared__ float hh[HID];
    int g = blockIdx.x, t = threadIdx.x;
    hg[t]           = pool1[(size_t)g * HID + t];
    hg[HID + t]     = pool2[(size_t)g * HID + t];
    hg[2 * HID + t] = pool3[(size_t)g * HID + t];
    if (t < EXD) hg[3 * HID + t] = eF[(size_t)g * EXD + t];
    __syncthreads();
    float acc = fc1b[t];
    for (int k = 0; k < 3 * HID + EXD; ++k) acc += hg[k] * fc1W[(size_t)k * HID + t];
    hh[t] = fmaxf(acc, 0.f);
    __syncthreads();
    if (t < OUTD) {
        float a2 = fc3b[t];
        for (int k = 0; k < HID; ++k) a2 += hh[k] * fc3W[(size_t)k * OUTD + t];
        out[(size_t)g * OUTD + t] = a2;
    }
}

// ---------------- launch ----------------

extern "C" void kernel_launch(void* const* d_in, const int* in_sizes, int n_in,
                              void* d_out, int out_size, void* d_ws, size_t ws_size,
                              hipStream_t stream) {
    const float* x      = (const float*)d_in[0];
    const float* eF     = (const float*)d_in[1];
    const int*   ei     = (const int*)d_in[2];
    const int*   batch  = (const int*)d_in[3];
    const int* src = ei;
    const int* dst = ei + NE;

    const float* W1 = (const float*)d_in[4];  const float* b1 = (const float*)d_in[5];
    const float* W2 = (const float*)d_in[6];  const float* b2 = (const float*)d_in[7];
    const float* W3 = (const float*)d_in[8];  const float* b3 = (const float*)d_in[9];
    const float* g1 = (const float*)d_in[10]; const float* be1 = (const float*)d_in[11];
    const float* g2 = (const float*)d_in[12]; const float* be2 = (const float*)d_in[13];
    const float* g3 = (const float*)d_in[14]; const float* be3 = (const float*)d_in[15];
    const float* s1_Wp = (const float*)d_in[16];
    const float* s1_Wi = (const float*)d_in[17]; const float* s1_bi = (const float*)d_in[18];
    const float* s1_Wo = (const float*)d_in[19]; const float* s1_bo = (const float*)d_in[20];
    const float* s2_Wi = (const float*)d_in[21]; const float* s2_bi = (const float*)d_in[22];
    const float* s2_Wo = (const float*)d_in[23]; const float* s2_bo = (const float*)d_in[24];
    const float* s3_Wi = (const float*)d_in[25]; const float* s3_bi = (const float*)d_in[26];
    const float* s3_Wo = (const float*)d_in[27]; const float* s3_bo = (const float*)d_in[28];
    const float* fc1W = (const float*)d_in[29]; const float* fc1b = (const float*)d_in[30];
    const float* fc3W = (const float*)d_in[31]; const float* fc3b = (const float*)d_in[32];

    size_t S = (size_t)NN * HID;
    unsigned short* xwb  = (unsigned short*)d_ws;          // NN*HID
    unsigned short* xb   = xwb + S;                        // NN*IN_DIM
    unsigned short* hb   = xb + (size_t)NN * IN_DIM;       // NN*HID
    unsigned short* aggb = hb + S;                         // NN*HID
    unsigned short* wfb  = aggb + S;                       // 10*16384
    float* dinv = (float*)(wfb + 10 * 16384);              // NN
    int*   row_start = (int*)(dinv + NN);                  // NN+1
    int*   csr_src   = row_start + NN + 1;                 // NE
    int*   gstart    = csr_src + NE;                       // NG+1
    float* stats = (float*)(gstart + NG + 1);              // 6*128
    float* pools = stats + 6 * HID;                        // 3*NG*HID
    float* psum  = pools + 3 * (size_t)NG * HID;           // AGB*128
    float* psq   = psum + (size_t)AGB * 128;               // AGB*128
    // transient (aliased into xwb region, dead before first mgemm writes xwb):
    int* deg   = (int*)d_ws;                               // NN
    unsigned char* epos = (unsigned char*)((int*)d_ws + NN);  // NE bytes
    int* bsums = (int*)(epos + NE);                        // NBLK

    const int TB = 256;
    const int GB2 = (NN + 127) / 128;
    const int NB  = (NN + TB - 1) / TB;
    const int EB  = (NE + TB - 1) / TB;

    // frag-layout weight slots
    unsigned short* wfW1   = wfb + 0 * 16384;
    unsigned short* wfS1p  = wfb + 1 * 16384;
    unsigned short* wfS1i  = wfb + 2 * 16384;
    unsigned short* wfS1o  = wfb + 3 * 16384;
    unsigned short* wfW2   = wfb + 4 * 16384;
    unsigned short* wfS2i  = wfb + 5 * 16384;
    unsigned short* wfS2o  = wfb + 6 * 16384;
    unsigned short* wfW3   = wfb + 7 * 16384;
    unsigned short* wfS3i  = wfb + 8 * 16384;
    unsigned short* wfS3o  = wfb + 9 * 16384;

    WPack wp;
    wp.w[0] = W1;    wp.K[0] = IN_DIM;
    wp.w[1] = s1_Wp; wp.K[1] = IN_DIM;
    wp.w[2] = s1_Wi; wp.K[2] = HID;
    wp.w[3] = s1_Wo; wp.K[3] = HID;
    wp.w[4] = W2;    wp.K[4] = HID;
    wp.w[5] = s2_Wi; wp.K[5] = HID;
    wp.w[6] = s2_Wo; wp.K[6] = HID;
    wp.w[7] = W3;    wp.K[7] = HID;
    wp.w[8] = s3_Wi; wp.K[8] = HID;
    wp.w[9] = s3_Wo; wp.K[9] = HID;

    float* gsum1 = stats;            float* gsq1 = stats + HID;
    float* gsum2 = stats + 2 * HID;  float* gsq2 = stats + 3 * HID;
    float* gsum3 = stats + 4 * HID;  float* gsq3 = stats + 5 * HID;

    // ---- CSR build + fused prep (fill/gstart/cvt/wprep) ----
    hipMemsetAsync(deg, 0, NN * sizeof(int), stream);
    hipMemsetAsync(stats, 0, 6 * HID * sizeof(float), stream);
    degpos_kernel<<<EB, TB, 0, stream>>>(dst, deg, epos);
    scan1_kernel<<<NBLK, SCAN_B, 0, stream>>>(deg, row_start, bsums, dinv);
    scan2_kernel<<<1, 512, 0, stream>>>(bsums);
    scan3_kernel<<<NB, TB, 0, stream>>>(row_start, bsums);
    prep_kernel<<<FILL_B + GST_B + CVT_B + WPREP_B, TB, 0, stream>>>(
        src, dst, row_start, epos, csr_src, batch, gstart, x, xb, wp, wfb);

    // ---- layer 1 ----
    mgemm2_kernel<<<GB2, TB, 0, stream>>>(xb, wfW1, wfS1p, xwb, hb);
    gather_kernel<<<AGB, TB, 0, stream>>>(row_start, csr_src, xwb, dinv, b1, aggb, psum, psq);
    stats_reduce_kernel<<<32, TB, 0, stream>>>(psum, psq, gsum1, gsq1);
    mgemm_kernel<<<GB2, TB, 0, stream>>>(aggb, wfS1o, HID, hb, wfS1i, HID,
                                         s1_bo, s1_bi, aggb, gsum1, gsq1, g1, be1, hb, 1);
    pool_kernel<<<NG, TB, 0, stream>>>(hb, gstart, pools);

    // ---- layer 2 ----
    mgemm_kernel<<<GB2, TB, 0, stream>>>(hb, wfW2, HID, nullptr, nullptr, 0,
                                         nullptr, nullptr, nullptr,
                                         nullptr, nullptr, nullptr, nullptr, xwb, 2);
    gather_kernel<<<AGB, TB, 0, stream>>>(row_start, csr_src, xwb, dinv, b2, aggb, psum, psq);
    stats_reduce_kernel<<<32, TB, 0, stream>>>(psum, psq, gsum2, gsq2);
    mgemm_kernel<<<GB2, TB, 0, stream>>>(aggb, wfS2o, HID, hb, wfS2i, HID,
                                         s2_bo, s2_bi, aggb, gsum2, gsq2, g2, be2, hb, 1);
    pool_kernel<<<NG, TB, 0, stream>>>(hb, gstart, pools + (size_t)NG * HID);

    // ---- layer 3 ----
    mgemm_kernel<<<GB2, TB, 0, stream>>>(hb, wfW3, HID, nullptr, nullptr, 0,
                                         nullptr, nullptr, nullptr,
                                         nullptr, nullptr, nullptr, nullptr, xwb, 2);
    gather_kernel<<<AGB, TB, 0, stream>>>(row_start, csr_src, xwb, dinv, b3, aggb, psum, psq);
    stats_reduce_kernel<<<32, TB, 0, stream>>>(psum, psq, gsum3, gsq3);
    mgemm_kernel<<<GB2, TB, 0, stream>>>(aggb, wfS3o, HID, hb, wfS3i, HID,
                                         s3_bo, s3_bi, aggb, gsum3, gsq3, g3, be3, hb, 1);
    pool_kernel<<<NG, TB, 0, stream>>>(hb, gstart, pools + 2 * (size_t)NG * HID);

    // ---- head ----
    head_kernel<<<NG, HID, 0, stream>>>(pools, pools + (size_t)NG * HID,
                                        pools + 2 * (size_t)NG * HID, eF,
                                        fc1W, fc1b, fc3W, fc3b, (float*)d_out);
}

// Round 12
// 736.284 us; speedup vs baseline: 1.3198x; 1.3198x over previous
//
#include <hip/hip_runtime.h>
#include <math.h>

#define NN 100000
#define NE 1600000
#define NG 1000
#define IN_DIM 64
#define HID 128
#define EXD 32
#define OUTD 10
#define BN_EPS 1e-5f

#define SCAN_B 256
#define NBLK ((NN + SCAN_B - 1) / SCAN_B)   // 391

// XCD-partitioned edge placement (scattered csr writes stay XCD-local)
#define FCH 128
#define FCE (NE / FCH)          // 12500 edges per chunk
#define PR  ((NN + 7) / 8)      // 12500 nodes per part

#define AGB 12500               // gather blocks (8 nodes each, exact)
#define SRB 1024                // stats-reduce blocks
#define SRC_CH ((AGB + SRB - 1) / SRB)   // 13 partial rows per block

typedef __attribute__((ext_vector_type(8))) short bf16x8;
typedef __attribute__((ext_vector_type(4))) float f32x4;

__device__ __forceinline__ float bf2f(unsigned short h) {
    return __uint_as_float((unsigned int)h << 16);
}
__device__ __forceinline__ unsigned short f2bf(float f) {
    unsigned int u = __float_as_uint(f);
    u += 0x7fffu + ((u >> 16) & 1u);        // round to nearest even
    return (unsigned short)(u >> 16);
}

// ---------------- degree + per-edge position (one atomic pass) ----------------
// UNPARTITIONED (R10 post-mortem: atomic writeback is placement-invariant;
// partitioning only added dst re-reads + epos write amplification).

__global__ void degpos_kernel(const int* __restrict__ dst, int* __restrict__ deg,
                              unsigned char* __restrict__ epos) {
    int e = blockIdx.x * 256 + threadIdx.x;
    if (e < NE) epos[e] = (unsigned char)atomicAdd(&deg[dst[e]], 1);
}

// exclusive scan of deg -> row_start; also dinv = rsqrt(deg+1)
__global__ void scan1_kernel(const int* __restrict__ deg, int* __restrict__ row_start,
                             int* __restrict__ bsums, float* __restrict__ dinv) {
    __shared__ int s[SCAN_B];
    int t = threadIdx.x;
    int i = blockIdx.x * SCAN_B + t;
    int v = (i < NN) ? deg[i] : 0;
    if (i < NN) dinv[i] = rsqrtf((float)v + 1.0f);   // +1 self loop
    s[t] = v;
    __syncthreads();
    for (int off = 1; off < SCAN_B; off <<= 1) {
        int u = (t >= off) ? s[t - off] : 0;
        __syncthreads();
        s[t] += u;
        __syncthreads();
    }
    if (i < NN) row_start[i] = s[t] - v;
    if (t == SCAN_B - 1) bsums[blockIdx.x] = s[t];
}

__global__ void scan2_kernel(int* __restrict__ bsums) {
    __shared__ int s[512];
    int t = threadIdx.x;
    int v = (t < NBLK) ? bsums[t] : 0;
    s[t] = v;
    __syncthreads();
    for (int off = 1; off < 512; off <<= 1) {
        int u = (t >= off) ? s[t - off] : 0;
        __syncthreads();
        s[t] += u;
        __syncthreads();
    }
    if (t < NBLK) bsums[t] = s[t] - v;
}

__global__ void scan3_kernel(int* __restrict__ row_start, const int* __restrict__ bsums) {
    int i = blockIdx.x * 256 + threadIdx.x;
    if (i < NN) row_start[i] += bsums[i >> 8];
    if (i == 0) row_start[NN] = NE;
}

// ---------------- fused prep: fill + gstart + cvt + wprep (one launch) ----------------

struct WPack {
    const float* w[10];
    int K[10];
};

#define FILL_B (FCH * 8)                       // 1024
#define GST_B  NBLK                            // 391
#define CVT_B  ((NN * 16 + 255) / 256)         // 6250
#define WPREP_B 640                            // 10 matrices x 64

__global__ void prep_kernel(const int* __restrict__ src, const int* __restrict__ dst,
                            const int* __restrict__ row_start,
                            const unsigned char* __restrict__ epos,
                            int* __restrict__ csr_src,
                            const int* __restrict__ batch, int* __restrict__ gstart,
                            const float* __restrict__ x, unsigned short* __restrict__ xb,
                            WPack wp, unsigned short* __restrict__ wf) {
    int b = blockIdx.x;
    int tid = threadIdx.x;
    if (b < FILL_B) {
        // edge placement: slot = row_start[dst] + epos[e]; partitioned writes
        int part = b & 7;
        int lo = part * PR, hi = min(lo + PR, NN);
        int e0 = (b >> 3) * FCE;
        for (int e = e0 + tid; e < e0 + FCE; e += 256) {
            int d = dst[e];
            if (d >= lo && d < hi) csr_src[row_start[d] + (int)epos[e]] = src[e];
        }
    } else if (b < FILL_B + GST_B) {
        int n = (b - FILL_B) * 256 + tid;
        if (n >= NN) return;
        int bc = batch[n];
        int bp = (n == 0) ? -1 : batch[n - 1];
        for (int g = bp + 1; g <= bc; ++g) gstart[g] = n;
        if (n == NN - 1)
            for (int g = bc + 1; g <= NG; ++g) gstart[g] = NN;
    } else if (b < FILL_B + GST_B + CVT_B) {
        int i = (b - FILL_B - GST_B) * 256 + tid;
        if (i >= NN * 16) return;
        float4 v = ((const float4*)x)[i];
        ushort4 o;
        o.x = f2bf(v.x); o.y = f2bf(v.y); o.z = f2bf(v.z); o.w = f2bf(v.w);
        ((ushort4*)xb)[i] = o;
    } else {
        int b2 = b - FILL_B - GST_B - CVT_B;
        int m = b2 >> 6;
        int idx = ((b2 & 63) << 8) + tid;
        int K = wp.K[m];
        if (idx >= K * 128) return;
        int k = idx >> 7, n = idx & 127;
        wf[m * 16384 + (((k >> 3) * 128 + n) << 3) + (k & 7)] = f2bf(wp.w[m][idx]);
    }
}

// ---------------- GCN aggregation: pull-gather + fused BN partial stats ----------------
// 8 nodes per block, 32 lanes per node, lane covers feats [4*lane .. 4*lane+3].
// Epilogue: block-level LDS reduction -> per-block partial sum/sumsq (coalesced).
__launch_bounds__(256)
__global__ void gather_kernel(const int* __restrict__ row_start,
                              const int* __restrict__ csr_src,
                              const unsigned short* __restrict__ xwb,
                              const float* __restrict__ dinv,
                              const float* __restrict__ b,
                              unsigned short* __restrict__ aggb,
                              float* __restrict__ psum, float* __restrict__ psq) {
    __shared__ float rsm[8][128];
    __shared__ float rqm[8][128];
    int node = blockIdx.x * 8 + (threadIdx.x >> 5);
    int lane = threadIdx.x & 31;
    int rs = row_start[node], re = row_start[node + 1];
    float d = dinv[node];
    int fo = lane << 2;
    ushort4 sv = *(const ushort4*)(xwb + (size_t)node * HID + fo);
    float4 accE = make_float4(0.f, 0.f, 0.f, 0.f);
    int e = rs;
    for (; e + 7 < re; e += 8) {
        int sI[8];
#pragma unroll
        for (int j = 0; j < 8; ++j) sI[j] = csr_src[e + j];
        float cI[8];
        ushort4 rI[8];
#pragma unroll
        for (int j = 0; j < 8; ++j) {
            cI[j] = dinv[sI[j]];
            rI[j] = *(const ushort4*)(xwb + (size_t)sI[j] * HID + fo);
        }
#pragma unroll
        for (int j = 0; j < 8; ++j) {
            accE.x += cI[j] * bf2f(rI[j].x);
            accE.y += cI[j] * bf2f(rI[j].y);
            accE.z += cI[j] * bf2f(rI[j].z);
            accE.w += cI[j] * bf2f(rI[j].w);
        }
    }
    for (; e + 1 < re; e += 2) {
        int s0 = csr_src[e], s1 = csr_src[e + 1];
        float c0 = dinv[s0], c1 = dinv[s1];
        ushort4 r0 = *(const ushort4*)(xwb + (size_t)s0 * HID + fo);
        ushort4 r1 = *(const ushort4*)(xwb + (size_t)s1 * HID + fo);
        accE.x += c0 * bf2f(r0.x) + c1 * bf2f(r1.x);
        accE.y += c0 * bf2f(r0.y) + c1 * bf2f(r1.y);
        accE.z += c0 * bf2f(r0.z) + c1 * bf2f(r1.z);
        accE.w += c0 * bf2f(r0.w) + c1 * bf2f(r1.w);
    }
    if (e < re) {
        int s0 = csr_src[e];
        float c0 = dinv[s0];
        ushort4 r0 = *(const ushort4*)(xwb + (size_t)s0 * HID + fo);
        accE.x += c0 * bf2f(r0.x);
        accE.y += c0 * bf2f(r0.y);
        accE.z += c0 * bf2f(r0.z);
        accE.w += c0 * bf2f(r0.w);
    }
    float d2 = d * d;
    ushort4 o;
    o.x = f2bf(d * accE.x + d2 * bf2f(sv.x) + b[fo + 0]);
    o.y = f2bf(d * accE.y + d2 * bf2f(sv.y) + b[fo + 1]);
    o.z = f2bf(d * accE.z + d2 * bf2f(sv.z) + b[fo + 2]);
    o.w = f2bf(d * accE.w + d2 * bf2f(sv.w) + b[fo + 3]);
    *(ushort4*)(aggb + (size_t)node * HID + fo) = o;

    // ---- fused BN partial stats (on the bf16-rounded values) ----
    float v0 = bf2f(o.x), v1 = bf2f(o.y), v2 = bf2f(o.z), v3 = bf2f(o.w);
    int sub = threadIdx.x >> 5;
    rsm[sub][fo + 0] = v0; rsm[sub][fo + 1] = v1;
    rsm[sub][fo + 2] = v2; rsm[sub][fo + 3] = v3;
    rqm[sub][fo + 0] = v0 * v0; rqm[sub][fo + 1] = v1 * v1;
    rqm[sub][fo + 2] = v2 * v2; rqm[sub][fo + 3] = v3 * v3;
    __syncthreads();
    int t = threadIdx.x;
    if (t < 128) {
        float s = 0.f, q = 0.f;
#pragma unroll
        for (int i = 0; i < 8; ++i) { s += rsm[i][t]; q += rqm[i][t]; }
        psum[(size_t)blockIdx.x * 128 + t] = s;
        psq[(size_t)blockIdx.x * 128 + t] = q;
    }
}

// reduce per-block partials -> gsum/gsq.
// SRB=1024 blocks x ~13 rows each (R11 post-mortem: 32 blocks = 1.2% occupancy,
// 115 us; need full-grid parallelism). 262K total atomics, same as old bn_stats.
__global__ void stats_reduce_kernel(const float* __restrict__ psum,
                                    const float* __restrict__ psq,
                                    float* __restrict__ gsum, float* __restrict__ gsq) {
    int t = threadIdx.x;            // 256
    int c = t & 127;
    bool isq = t >= 128;
    const float* p = isq ? psq : psum;
    int b0 = blockIdx.x * SRC_CH;
    int b1 = min(b0 + SRC_CH, AGB);
    float s = 0.f;
    for (int bi = b0; bi < b1; ++bi)
        s += p[(size_t)bi * 128 + c];
    atomicAdd(isq ? &gsq[c] : &gsum[c], s);
}

// ---------------- MFMA GEMM (bf16 in, f32 acc, bf16 out) ----------------
// Block: 256 thr / 4 waves; tile 128 rows x 128 cols; wave owns 32 rows in K-loop.
// W (pre-formatted wf) staged into LDS per pass; B-frags via ds_read_b128.
// LDS buffer reused for epilogue C tile (barrier-separated) -> 4 blocks/CU.
// mode 2: target = bf16(A1 @ Wa)
// mode 1: BN finalize in-kernel (scl/shf from gsum/gsq/g/be into LDS);
//         ox = relu(A1*scl+shf); t = ox@Wa + A2@Wb + b1 + b2; z = sigmoid(t);
//         target = bf16(z*ox + (1-z)*target)    (target aliases A2)
#define CS_STRIDE 136
#define LW_STRIDE 1032          // shorts per k-chunk (1024 data + 8 pad)
__launch_bounds__(256, 4)
__global__ void mgemm_kernel(const unsigned short* __restrict__ A1,
                             const unsigned short* __restrict__ wfA, int K1,
                             const unsigned short* A2,
                             const unsigned short* __restrict__ wfB, int K2,
                             const float* __restrict__ bias1, const float* __restrict__ bias2,
                             const unsigned short* outx,
                             const float* __restrict__ gsum, const float* __restrict__ gsq,
                             const float* __restrict__ gw, const float* __restrict__ bew,
                             unsigned short* target, int mode) {
    __shared__ unsigned short sm[128 * CS_STRIDE];   // W-stage / C-stage
    __shared__ float sclS[128], shfS[128];
    int tid = threadIdx.x;
    int lane = tid & 63;
    int wv = tid >> 6;
    int lane15 = lane & 15;
    int q = lane >> 4;
    int m0 = blockIdx.x * 128 + wv * 32;

    if (mode == 1 && tid < 128) {
        float mu = gsum[tid] * (1.0f / NN);
        float var = gsq[tid] * (1.0f / NN) - mu * mu;
        float sc = gw[tid] * rsqrtf(var + BN_EPS);
        sclS[tid] = sc;
        shfS[tid] = bew[tid] - mu * sc;
    }

    f32x4 acc[2][8];
#pragma unroll
    for (int r = 0; r < 2; ++r)
#pragma unroll
        for (int nt = 0; nt < 8; ++nt)
            acc[r][nt] = (f32x4){0.f, 0.f, 0.f, 0.f};

    bf16x8 zf = {0, 0, 0, 0, 0, 0, 0, 0};

    for (int p = 0; p < 2; ++p) {
        const unsigned short* A = p ? A2 : A1;
        const unsigned short* wf = p ? wfB : wfA;
        int K = p ? K2 : K1;
        if (K == 0) continue;
        bool bnA = (mode == 1) && (p == 0);
        __syncthreads();
        for (int g = tid; g < K * 16; g += 256) {
            int c = g >> 7, off = (g & 127) << 3;
            *(bf16x8*)&sm[c * LW_STRIDE + off] = *(const bf16x8*)&wf[(c << 10) + off];
        }
        __syncthreads();
        int row0 = m0 + lane15;
        const unsigned short* a0p = A + (size_t)row0 * K + (q << 3);
        const unsigned short* a1p = a0p + (size_t)16 * K;
        bool g0 = row0 < NN, g1 = (row0 + 16) < NN;
#pragma unroll 4
        for (int k0 = 0; k0 < K; k0 += 32) {
            bf16x8 af0 = zf, af1 = zf;
            if (g0) af0 = *(const bf16x8*)(a0p + k0);
            if (g1) af1 = *(const bf16x8*)(a1p + k0);
            if (bnA) {
                int kb = k0 + (q << 3);
                float4 s4a = *(const float4*)&sclS[kb];
                float4 s4b = *(const float4*)&sclS[kb + 4];
                float4 h4a = *(const float4*)&shfS[kb];
                float4 h4b = *(const float4*)&shfS[kb + 4];
                float sv[8] = {s4a.x, s4a.y, s4a.z, s4a.w, s4b.x, s4b.y, s4b.z, s4b.w};
                float hv[8] = {h4a.x, h4a.y, h4a.z, h4a.w, h4b.x, h4b.y, h4b.z, h4b.w};
#pragma unroll
                for (int j = 0; j < 8; ++j) {
                    af0[j] = (short)f2bf(fmaxf(bf2f((unsigned short)af0[j]) * sv[j] + hv[j], 0.f));
                    af1[j] = (short)f2bf(fmaxf(bf2f((unsigned short)af1[j]) * sv[j] + hv[j], 0.f));
                }
            }
            const unsigned short* wb = &sm[((k0 >> 3) + q) * LW_STRIDE + (lane15 << 3)];
#pragma unroll
            for (int nt = 0; nt < 8; ++nt) {
                bf16x8 bf = *(const bf16x8*)(wb + nt * 128);
                acc[0][nt] = __builtin_amdgcn_mfma_f32_16x16x32_bf16(af0, bf, acc[0][nt], 0, 0, 0);
                acc[1][nt] = __builtin_amdgcn_mfma_f32_16x16x32_bf16(af1, bf, acc[1][nt], 0, 0, 0);
            }
        }
    }
    __syncthreads();

    if (mode == 1) {
        float bsum[8];
#pragma unroll
        for (int nt = 0; nt < 8; ++nt)
            bsum[nt] = bias1[nt * 16 + lane15] + bias2[nt * 16 + lane15];
#pragma unroll
        for (int r = 0; r < 2; ++r)
#pragma unroll
            for (int nt = 0; nt < 8; ++nt)
#pragma unroll
                for (int g = 0; g < 4; ++g) {
                    int rr = wv * 32 + r * 16 + q * 4 + g;
                    sm[rr * CS_STRIDE + nt * 16 + lane15] = f2bf(acc[r][nt][g] + bsum[nt]);
                }
    } else {
#pragma unroll
        for (int r = 0; r < 2; ++r)
#pragma unroll
            for (int nt = 0; nt < 8; ++nt)
#pragma unroll
                for (int g = 0; g < 4; ++g) {
                    int rr = wv * 32 + r * 16 + q * 4 + g;
                    sm[rr * CS_STRIDE + nt * 16 + lane15] = f2bf(acc[r][nt][g]);
                }
    }
    __syncthreads();

#pragma unroll
    for (int i = 0; i < 8; ++i) {
        int rt = (tid >> 4) + i * 16;
        int ch = tid & 15;
        int row = blockIdx.x * 128 + rt;
        if (row >= NN) continue;
        bf16x8 c = *(const bf16x8*)(sm + rt * CS_STRIDE + (ch << 3));
        size_t off = (size_t)row * HID + (ch << 3);
        if (mode == 1) {
            int cb = ch << 3;
            float4 s4a = *(const float4*)&sclS[cb];
            float4 s4b = *(const float4*)&sclS[cb + 4];
            float4 h4a = *(const float4*)&shfS[cb];
            float4 h4b = *(const float4*)&shfS[cb + 4];
            float sv[8] = {s4a.x, s4a.y, s4a.z, s4a.w, s4b.x, s4b.y, s4b.z, s4b.w};
            float hv[8] = {h4a.x, h4a.y, h4a.z, h4a.w, h4b.x, h4b.y, h4b.z, h4b.w};
            bf16x8 oxv = *(const bf16x8*)(outx + off);
            bf16x8 ixv = *(const bf16x8*)(target + off);
            bf16x8 o;
#pragma unroll
            for (int j = 0; j < 8; ++j) {
                float t = bf2f((unsigned short)c[j]);
                float z = 1.0f / (1.0f + expf(-t));
                float ox = fmaxf(bf2f((unsigned short)oxv[j]) * sv[j] + hv[j], 0.f);
                float h = z * ox + (1.0f - z) * bf2f((unsigned short)ixv[j]);
                o[j] = (short)f2bf(h);
            }
            *(bf16x8*)(target + off) = o;
        } else {
            *(bf16x8*)(target + off) = c;
        }
    }
}

// ---------------- dual-output GEMM for layer 1 (K=64, two W sets) ----------------
__launch_bounds__(256, 2)
__global__ void mgemm2_kernel(const unsigned short* __restrict__ A,
                              const unsigned short* __restrict__ wfA,
                              const unsigned short* __restrict__ wfB,
                              unsigned short* __restrict__ t0,
                              unsigned short* __restrict__ t1) {
    __shared__ unsigned short sm[128 * CS_STRIDE];
    int tid = threadIdx.x;
    int lane = tid & 63;
    int wv = tid >> 6;
    int lane15 = lane & 15;
    int q = lane >> 4;
    int m0 = blockIdx.x * 128 + wv * 32;

    for (int g = tid; g < 2048; g += 256) {
        int w = g >> 10;
        int c = (g >> 7) & 7;
        int off = (g & 127) << 3;
        const unsigned short* wf = w ? wfB : wfA;
        *(bf16x8*)&sm[(w * 8 + c) * LW_STRIDE + off] = *(const bf16x8*)&wf[(c << 10) + off];
    }
    __syncthreads();

    f32x4 acc[2][2][8];
#pragma unroll
    for (int w = 0; w < 2; ++w)
#pragma unroll
        for (int r = 0; r < 2; ++r)
#pragma unroll
            for (int nt = 0; nt < 8; ++nt)
                acc[w][r][nt] = (f32x4){0.f, 0.f, 0.f, 0.f};

    bf16x8 zf = {0, 0, 0, 0, 0, 0, 0, 0};
    int row0 = m0 + lane15;
    const unsigned short* a0p = A + (size_t)row0 * IN_DIM + (q << 3);
    const unsigned short* a1p = a0p + (size_t)16 * IN_DIM;
    bool g0 = row0 < NN, g1 = (row0 + 16) < NN;
#pragma unroll
    for (int k0 = 0; k0 < IN_DIM; k0 += 32) {
        bf16x8 af0 = zf, af1 = zf;
        if (g0) af0 = *(const bf16x8*)(a0p + k0);
        if (g1) af1 = *(const bf16x8*)(a1p + k0);
#pragma unroll
        for (int w = 0; w < 2; ++w) {
            const unsigned short* wb = &sm[(w * 8 + (k0 >> 3) + q) * LW_STRIDE + (lane15 << 3)];
#pragma unroll
            for (int nt = 0; nt < 8; ++nt) {
                bf16x8 bf = *(const bf16x8*)(wb + nt * 128);
                acc[w][0][nt] = __builtin_amdgcn_mfma_f32_16x16x32_bf16(af0, bf, acc[w][0][nt], 0, 0, 0);
                acc[w][1][nt] = __builtin_amdgcn_mfma_f32_16x16x32_bf16(af1, bf, acc[w][1][nt], 0, 0, 0);
            }
        }
    }

    for (int w = 0; w < 2; ++w) {
        unsigned short* target = w ? t1 : t0;
        __syncthreads();
#pragma unroll
        for (int r = 0; r < 2; ++r)
#pragma unroll
            for (int nt = 0; nt < 8; ++nt)
#pragma unroll
                for (int g = 0; g < 4; ++g) {
                    int rr = wv * 32 + r * 16 + q * 4 + g;
                    sm[rr * CS_STRIDE + nt * 16 + lane15] = f2bf(acc[w][r][nt][g]);
                }
        __syncthreads();
#pragma unroll
        for (int i = 0; i < 8; ++i) {
            int rt = (tid >> 4) + i * 16;
            int ch = tid & 15;
            int row = blockIdx.x * 128 + rt;
            if (row >= NN) continue;
            bf16x8 c = *(const bf16x8*)(sm + rt * CS_STRIDE + (ch << 3));
            *(bf16x8*)(target + (size_t)row * HID + (ch << 3)) = c;
        }
    }
}

// ---------------- pooling (segment-based, bf16 input) ----------------

__global__ void pool_kernel(const unsigned short* __restrict__ h,
                            const int* __restrict__ gstart,
                            float* __restrict__ pool) {
    __shared__ float red[8][128];
    int g = blockIdx.x, t = threadIdx.x;
    int lane = t & 31, sub = t >> 5;
    int s = gstart[g], e = gstart[g + 1];
    float4 acc = make_float4(0.f, 0.f, 0.f, 0.f);
    for (int r = s + sub; r < e; r += 8) {
        ushort4 v = *(const ushort4*)(h + (size_t)r * HID + (lane << 2));
        acc.x += bf2f(v.x); acc.y += bf2f(v.y);
        acc.z += bf2f(v.z); acc.w += bf2f(v.w);
    }
    *(float4*)&red[sub][lane << 2] = acc;
    __syncthreads();
    if (t < 128) {
        float a = 0.f;
#pragma unroll
        for (int i = 0; i < 8; ++i) a += red[i][t];
        pool[(size_t)g * HID + t] = a / (float)max(e - s, 1);
    }
}

// ---------------- MLP head ----------------

__global__ void head_kernel(const float* __restrict__ pool1, const float* __restrict__ pool2,
                            const float* __restrict__ pool3,
                            const float* __restrict__ eF,
                            const float* __restrict__ fc1W, const float* __restrict__ fc1b,
                            const float* __restrict__ fc3W, const float* __restrict__ fc3b,
                            float* __restrict__ out) {
    __shared__ float hg[3 * HID + EXD];
    __shared__ float hh[HID];
    int g = blockIdx.x, t = threadIdx.x;
    hg[t]           = pool1[(size_t)g * HID + t];
    hg[HID + t]     = pool2[(size_t)g * HID + t];
    hg[2 * HID + t] = pool3[(size_t)g * HID + t];
    if (t < EXD) hg[3 * HID + t] = eF[(size_t)g * EXD + t];
    __syncthreads();
    float acc = fc1b[t];
    for (int k = 0; k < 3 * HID + EXD; ++k) acc += hg[k] * fc1W[(size_t)k * HID + t];
    hh[t] = fmaxf(acc, 0.f);
    __syncthreads();
    if (t < OUTD) {
        float a2 = fc3b[t];
        for (int k = 0; k < HID; ++k) a2 += hh[k] * fc3W[(size_t)k * OUTD + t];
        out[(size_t)g * OUTD + t] = a2;
    }
}

// ---------------- launch ----------------

extern "C" void kernel_launch(void* const* d_in, const int* in_sizes, int n_in,
                              void* d_out, int out_size, void* d_ws, size_t ws_size,
                              hipStream_t stream) {
    const float* x      = (const float*)d_in[0];
    const float* eF     = (const float*)d_in[1];
    const int*   ei     = (const int*)d_in[2];
    const int*   batch  = (const int*)d_in[3];
    const int* src = ei;
    const int* dst = ei + NE;

    const float* W1 = (const float*)d_in[4];  const float* b1 = (const float*)d_in[5];
    const float* W2 = (const float*)d_in[6];  const float* b2 = (const float*)d_in[7];
    const float* W3 = (const float*)d_in[8];  const float* b3 = (const float*)d_in[9];
    const float* g1 = (const float*)d_in[10]; const float* be1 = (const float*)d_in[11];
    const float* g2 = (const float*)d_in[12]; const float* be2 = (const float*)d_in[13];
    const float* g3 = (const float*)d_in[14]; const float* be3 = (const float*)d_in[15];
    const float* s1_Wp = (const float*)d_in[16];
    const float* s1_Wi = (const float*)d_in[17]; const float* s1_bi = (const float*)d_in[18];
    const float* s1_Wo = (const float*)d_in[19]; const float* s1_bo = (const float*)d_in[20];
    const float* s2_Wi = (const float*)d_in[21]; const float* s2_bi = (const float*)d_in[22];
    const float* s2_Wo = (const float*)d_in[23]; const float* s2_bo = (const float*)d_in[24];
    const float* s3_Wi = (const float*)d_in[25]; const float* s3_bi = (const float*)d_in[26];
    const float* s3_Wo = (const float*)d_in[27]; const float* s3_bo = (const float*)d_in[28];
    const float* fc1W = (const float*)d_in[29]; const float* fc1b = (const float*)d_in[30];
    const float* fc3W = (const float*)d_in[31]; const float* fc3b = (const float*)d_in[32];

    size_t S = (size_t)NN * HID;
    unsigned short* xwb  = (unsigned short*)d_ws;          // NN*HID
    unsigned short* xb   = xwb + S;                        // NN*IN_DIM
    unsigned short* hb   = xb + (size_t)NN * IN_DIM;       // NN*HID
    unsigned short* aggb = hb + S;                         // NN*HID
    unsigned short* wfb  = aggb + S;                       // 10*16384
    float* dinv = (float*)(wfb + 10 * 16384);              // NN
    int*   row_start = (int*)(dinv + NN);                  // NN+1
    int*   csr_src   = row_start + NN + 1;                 // NE
    int*   gstart    = csr_src + NE;                       // NG+1
    float* stats = (float*)(gstart + NG + 1);              // 6*128
    float* pools = stats + 6 * HID;                        // 3*NG*HID
    float* psum  = pools + 3 * (size_t)NG * HID;           // AGB*128
    float* psq   = psum + (size_t)AGB * 128;               // AGB*128
    // transient (aliased into xwb region, dead before first mgemm writes xwb):
    int* deg   = (int*)d_ws;                               // NN
    unsigned char* epos = (unsigned char*)((int*)d_ws + NN);  // NE bytes
    int* bsums = (int*)(epos + NE);                        // NBLK

    const int TB = 256;
    const int GB2 = (NN + 127) / 128;
    const int NB  = (NN + TB - 1) / TB;
    const int EB  = (NE + TB - 1) / TB;

    // frag-layout weight slots
    unsigned short* wfW1   = wfb + 0 * 16384;
    unsigned short* wfS1p  = wfb + 1 * 16384;
    unsigned short* wfS1i  = wfb + 2 * 16384;
    unsigned short* wfS1o  = wfb + 3 * 16384;
    unsigned short* wfW2   = wfb + 4 * 16384;
    unsigned short* wfS2i  = wfb + 5 * 16384;
    unsigned short* wfS2o  = wfb + 6 * 16384;
    unsigned short* wfW3   = wfb + 7 * 16384;
    unsigned short* wfS3i  = wfb + 8 * 16384;
    unsigned short* wfS3o  = wfb + 9 * 16384;

    WPack wp;
    wp.w[0] = W1;    wp.K[0] = IN_DIM;
    wp.w[1] = s1_Wp; wp.K[1] = IN_DIM;
    wp.w[2] = s1_Wi; wp.K[2] = HID;
    wp.w[3] = s1_Wo; wp.K[3] = HID;
    wp.w[4] = W2;    wp.K[4] = HID;
    wp.w[5] = s2_Wi; wp.K[5] = HID;
    wp.w[6] = s2_Wo; wp.K[6] = HID;
    wp.w[7] = W3;    wp.K[7] = HID;
    wp.w[8] = s3_Wi; wp.K[8] = HID;
    wp.w[9] = s3_Wo; wp.K[9] = HID;

    float* gsum1 = stats;            float* gsq1 = stats + HID;
    float* gsum2 = stats + 2 * HID;  float* gsq2 = stats + 3 * HID;
    float* gsum3 = stats + 4 * HID;  float* gsq3 = stats + 5 * HID;

    // ---- CSR build + fused prep (fill/gstart/cvt/wprep) ----
    hipMemsetAsync(deg, 0, NN * sizeof(int), stream);
    hipMemsetAsync(stats, 0, 6 * HID * sizeof(float), stream);
    degpos_kernel<<<EB, TB, 0, stream>>>(dst, deg, epos);
    scan1_kernel<<<NBLK, SCAN_B, 0, stream>>>(deg, row_start, bsums, dinv);
    scan2_kernel<<<1, 512, 0, stream>>>(bsums);
    scan3_kernel<<<NB, TB, 0, stream>>>(row_start, bsums);
    prep_kernel<<<FILL_B + GST_B + CVT_B + WPREP_B, TB, 0, stream>>>(
        src, dst, row_start, epos, csr_src, batch, gstart, x, xb, wp, wfb);

    // ---- layer 1 ----
    mgemm2_kernel<<<GB2, TB, 0, stream>>>(xb, wfW1, wfS1p, xwb, hb);
    gather_kernel<<<AGB, TB, 0, stream>>>(row_start, csr_src, xwb, dinv, b1, aggb, psum, psq);
    stats_reduce_kernel<<<SRB, TB, 0, stream>>>(psum, psq, gsum1, gsq1);
    mgemm_kernel<<<GB2, TB, 0, stream>>>(aggb, wfS1o, HID, hb, wfS1i, HID,
                                         s1_bo, s1_bi, aggb, gsum1, gsq1, g1, be1, hb, 1);
    pool_kernel<<<NG, TB, 0, stream>>>(hb, gstart, pools);

    // ---- layer 2 ----
    mgemm_kernel<<<GB2, TB, 0, stream>>>(hb, wfW2, HID, nullptr, nullptr, 0,
                                         nullptr, nullptr, nullptr,
                                         nullptr, nullptr, nullptr, nullptr, xwb, 2);
    gather_kernel<<<AGB, TB, 0, stream>>>(row_start, csr_src, xwb, dinv, b2, aggb, psum, psq);
    stats_reduce_kernel<<<SRB, TB, 0, stream>>>(psum, psq, gsum2, gsq2);
    mgemm_kernel<<<GB2, TB, 0, stream>>>(aggb, wfS2o, HID, hb, wfS2i, HID,
                                         s2_bo, s2_bi, aggb, gsum2, gsq2, g2, be2, hb, 1);
    pool_kernel<<<NG, TB, 0, stream>>>(hb, gstart, pools + (size_t)NG * HID);

    // ---- layer 3 ----
    mgemm_kernel<<<GB2, TB, 0, stream>>>(hb, wfW3, HID, nullptr, nullptr, 0,
                                         nullptr, nullptr, nullptr,
                                         nullptr, nullptr, nullptr, nullptr, xwb, 2);
    gather_kernel<<<AGB, TB, 0, stream>>>(row_start, csr_src, xwb, dinv, b3, aggb, psum, psq);
    stats_reduce_kernel<<<SRB, TB, 0, stream>>>(psum, psq, gsum3, gsq3);
    mgemm_kernel<<<GB2, TB, 0, stream>>>(aggb, wfS3o, HID, hb, wfS3i, HID,
                                         s3_bo, s3_bi, aggb, gsum3, gsq3, g3, be3, hb, 1);
    pool_kernel<<<NG, TB, 0, stream>>>(hb, gstart, pools + 2 * (size_t)NG * HID);

    // ---- head ----
    head_kernel<<<NG, HID, 0, stream>>>(pools, pools + (size_t)NG * HID,
                                        pools + 2 * (size_t)NG * HID, eF,
                                        fc1W, fc1b, fc3W, fc3b, (float*)d_out);
}